// Round 11
// baseline (149.606 us; speedup 1.0000x reference)
//
#include <hip/hip_runtime.h>
#include <cstdint>
#include <cstddef>

typedef unsigned short u16;
typedef __attribute__((ext_vector_type(4))) float f32x4;
typedef __attribute__((ext_vector_type(8))) short bf16x8;
typedef __attribute__((ext_vector_type(4))) short bf16x4;

#define LN_EPS 1e-5f

__device__ __forceinline__ u16 f2bf(float f) {
  unsigned int u = __float_as_uint(f);
  u += 0x7FFFu + ((u >> 16) & 1u);
  return (u16)(u >> 16);
}

__device__ __forceinline__ float bf2f(short b) {
  return __uint_as_float(((unsigned)(unsigned short)b) << 16);
}

__device__ __forceinline__ float l0gate(float loga) {
  float s = 1.0f / (1.0f + expf(-loga));
  float v = s * 1.2f - 0.1f;   // sigmoid*(zeta-gamma)+gamma
  return fminf(fmaxf(v, 0.0f), 1.0f);
}

__device__ __forceinline__ void llds16(u16* lds, const u16* g) {
  __builtin_amdgcn_global_load_lds(
      (const __attribute__((address_space(1))) unsigned int*)g,
      (__attribute__((address_space(3))) unsigned int*)lds, 16, 0, 0);
}

// ---- prep: fold L0 gate into bf16 weights; also emit P=1/g, Q=ln_b/g ----
__global__ __launch_bounds__(256) void prep_weights(
    const float* __restrict__ dw, const float* __restrict__ uw,
    const float* __restrict__ dloga, const float* __restrict__ uloga,
    const int* __restrict__ lang, const float* __restrict__ g,
    const float* __restrict__ lnb,
    u16* __restrict__ dwb, u16* __restrict__ uwb, float* __restrict__ PQ) {
  const int lid = lang[0];
  const unsigned i = blockIdx.x * 256u + threadIdx.x;
  dwb[i] = f2bf(dw[i] * l0gate(dloga[lid * 2048 + (i & 2047u)]));
  uwb[i] = f2bf(uw[i] * l0gate(uloga[lid * 512 + (i & 511u)]));
  if (i < 2048u) {
    const float inv = 1.0f / g[i];
    PQ[2 * i] = inv;
    PQ[2 * i + 1] = lnb[i] * inv;
  }
}

// ---- LayerNorm over D=2048 + bf16 cast; stores per-row (mu, sigma) ----
__global__ __launch_bounds__(256) void ln_kernel(
    const float* __restrict__ x, const float* __restrict__ g,
    const float* __restrict__ b, u16* __restrict__ h1,
    float* __restrict__ ST) {
  const int row = blockIdx.x;
  const int tid = threadIdx.x;
  const float4* xr = (const float4*)(x + (size_t)row * 2048);
  float4 v0 = xr[tid * 2 + 0];
  float4 v1 = xr[tid * 2 + 1];
  float s = v0.x + v0.y + v0.z + v0.w + v1.x + v1.y + v1.z + v1.w;
  float q = v0.x * v0.x + v0.y * v0.y + v0.z * v0.z + v0.w * v0.w +
            v1.x * v1.x + v1.y * v1.y + v1.z * v1.z + v1.w * v1.w;
#pragma unroll
  for (int off = 32; off > 0; off >>= 1) {
    s += __shfl_down(s, off, 64);
    q += __shfl_down(q, off, 64);
  }
  __shared__ float ss[4], sq[4], sstat[2];
  const int wave = tid >> 6, lane = tid & 63;
  if (lane == 0) { ss[wave] = s; sq[wave] = q; }
  __syncthreads();
  if (tid == 0) {
    float S = ss[0] + ss[1] + ss[2] + ss[3];
    float Q = sq[0] + sq[1] + sq[2] + sq[3];
    float mu = S * (1.0f / 2048.0f);
    float var = Q * (1.0f / 2048.0f) - mu * mu;
    sstat[0] = mu;
    sstat[1] = rsqrtf(var + LN_EPS);
    ST[2 * row] = mu;
    ST[2 * row + 1] = sqrtf(var + LN_EPS);   // sigma (for x reconstruction)
  }
  __syncthreads();
  const float mu = sstat[0], rs = sstat[1];
  const float4* g4 = (const float4*)g;
  const float4* b4 = (const float4*)b;
  float4 ga = g4[tid * 2], gb = g4[tid * 2 + 1];
  float4 ba = b4[tid * 2], bb = b4[tid * 2 + 1];
  union { u16 us[8]; uint4 u; } p;
  p.us[0] = f2bf((v0.x - mu) * rs * ga.x + ba.x);
  p.us[1] = f2bf((v0.y - mu) * rs * ga.y + ba.y);
  p.us[2] = f2bf((v0.z - mu) * rs * ga.z + ba.z);
  p.us[3] = f2bf((v0.w - mu) * rs * ga.w + ba.w);
  p.us[4] = f2bf((v1.x - mu) * rs * gb.x + bb.x);
  p.us[5] = f2bf((v1.y - mu) * rs * gb.y + bb.y);
  p.us[6] = f2bf((v1.z - mu) * rs * gb.z + bb.z);
  p.us[7] = f2bf((v1.w - mu) * rs * gb.w + bb.w);
  ((uint4*)(h1 + (size_t)row * 2048))[tid] = p.u;
}

// ---- gemm1: h2 = relu(h1 * dwb^T + down_b), bf16 out (R9 version, unchanged) ----
__global__ __launch_bounds__(256) void gemm1(
    const u16* __restrict__ A, const u16* __restrict__ Bw,
    int M, int K, int NX,
    const float* __restrict__ bias,
    u16* __restrict__ outp) {
  const int N = 512;
  __shared__ __align__(16) char smem[65536];
  u16* As = (u16*)smem;
  u16* Bs = (u16*)(smem + 32768);
  float* Cs = (float*)smem;

  const int tid = threadIdx.x;
  const int wave = tid >> 6, lane = tid & 63;
  const int wr = (wave >> 1) * 64, wc = (wave & 1) * 64;
  const int lrow = lane & 15, lk = lane >> 4;

  const int nwg = gridDim.x;
  const int wg = (blockIdx.x & 7) * (nwg >> 3) + (blockIdx.x >> 3);
  const int bx = wg % NX, by = wg / NX;
  const size_t m0 = (size_t)by * 128, n0 = (size_t)bx * 128;

  f32x4 acc[4][4] = {};

  const int srow = lane >> 3;
  const int sslot = ((lane & 7) ^ ((lane >> 3) & 7)) * 8;
  auto STAGE = [&](int buf, int k0) {
#pragma unroll
    for (int c = 0; c < 4; ++c) {
      const int seg = c * 4 + wave;
      const int r = seg * 8 + srow;
      llds16(As + buf * 8192 + seg * 512, A + (m0 + r) * (size_t)K + (k0 + sslot));
      llds16(Bs + buf * 8192 + seg * 512, Bw + (n0 + r) * (size_t)K + (k0 + sslot));
    }
  };

  const int NT = K >> 6;
  STAGE(0, 0);

  for (int t = 0; t < NT; ++t) {
    const int cur = t & 1;
    if (t + 1 < NT) {
      STAGE(cur ^ 1, (t + 1) << 6);
      asm volatile("s_waitcnt vmcnt(8)" ::: "memory");
    } else {
      asm volatile("s_waitcnt vmcnt(0)" ::: "memory");
    }
    __builtin_amdgcn_s_barrier();
    asm volatile("" ::: "memory");

    const u16* Ab = As + cur * 8192;
    const u16* Bb = Bs + cur * 8192;
#pragma unroll
    for (int ks = 0; ks < 2; ++ks) {
      bf16x8 af[4], bfr[4];
#pragma unroll
      for (int m = 0; m < 4; ++m)
        af[m] = *(const bf16x8*)&Ab[(wr + m * 16 + lrow) * 64 +
                                    ((unsigned)((ks * 4 + lk) ^ (lane & 7))) * 8];
#pragma unroll
      for (int n = 0; n < 4; ++n)
        bfr[n] = *(const bf16x8*)&Bb[(wc + n * 16 + lrow) * 64 +
                                     ((unsigned)((ks * 4 + lk) ^ (lane & 7))) * 8];
      __builtin_amdgcn_s_setprio(1);
#pragma unroll
      for (int m = 0; m < 4; ++m)
#pragma unroll
        for (int n = 0; n < 4; ++n)
          acc[m][n] = __builtin_amdgcn_mfma_f32_16x16x32_bf16(af[m], bfr[n],
                                                              acc[m][n], 0, 0, 0);
      __builtin_amdgcn_s_setprio(0);
    }
    asm volatile("s_waitcnt lgkmcnt(0)" ::: "memory");
    __builtin_amdgcn_s_barrier();
    asm volatile("" ::: "memory");
  }

#pragma unroll
  for (int n = 0; n < 4; ++n) {
    const int c = wc + n * 16 + lrow;
    const float bv = bias[n0 + c];
#pragma unroll
    for (int m = 0; m < 4; ++m) {
#pragma unroll
      for (int r = 0; r < 4; ++r) {
        const int row = wr + m * 16 + lk * 4 + r;
        Cs[row * 128 + ((c + ((row >> 2) << 3)) & 127)] = acc[m][n][r] + bv;
      }
    }
  }
  asm volatile("s_waitcnt lgkmcnt(0)" ::: "memory");
  __builtin_amdgcn_s_barrier();
  asm volatile("" ::: "memory");

#pragma unroll
  for (int j = 0; j < 8; ++j) {
    const int flat = tid * 8 + j * 2048;
    const int row = flat >> 7, c = flat & 127;
    const int cp = (c + ((row >> 2) << 3)) & 127;
    const f32x4 c0 = *(const f32x4*)&Cs[row * 128 + cp];
    const f32x4 c1 = *(const f32x4*)&Cs[row * 128 + cp + 4];
    union { u16 us[8]; uint4 u; } p;
    p.us[0] = f2bf(fmaxf(c0[0], 0.0f)); p.us[1] = f2bf(fmaxf(c0[1], 0.0f));
    p.us[2] = f2bf(fmaxf(c0[2], 0.0f)); p.us[3] = f2bf(fmaxf(c0[3], 0.0f));
    p.us[4] = f2bf(fmaxf(c1[0], 0.0f)); p.us[5] = f2bf(fmaxf(c1[1], 0.0f));
    p.us[6] = f2bf(fmaxf(c1[2], 0.0f)); p.us[7] = f2bf(fmaxf(c1[3], 0.0f));
    *(uint4*)&outp[(m0 + row) * (size_t)N + n0 + c] = p.u;
  }
}

// ---- gemm2: out = h2*uwb^T + up_b + x_reconstructed; K=512, fully unrolled.
// resid = sg*(P*h1 - Q) + mu from warm bf16 h1 (no cold f32 x read).
__global__ __launch_bounds__(256) void gemm2(
    const u16* __restrict__ A, const u16* __restrict__ Bw,
    int M, const float* __restrict__ bias,
    const u16* __restrict__ h1, const float* __restrict__ PQ,
    const float* __restrict__ ST, float* __restrict__ outp) {
  const int K = 512, N = 2048;
  __shared__ __align__(16) char smem[65536];
  __shared__ __align__(16) float extra[512];  // [0..255]=P,Q pairs  [256..511]=mu,sig pairs
  u16* As = (u16*)smem;
  u16* Bs = (u16*)(smem + 32768);
  float* Cs = (float*)smem;

  const int tid = threadIdx.x;
  const int wave = tid >> 6, lane = tid & 63;
  const int wr = (wave >> 1) * 64, wc = (wave & 1) * 64;
  const int lrow = lane & 15, lk = lane >> 4;

  const int nwg = gridDim.x;            // 2048, %8==0
  const int wg = (blockIdx.x & 7) * (nwg >> 3) + (blockIdx.x >> 3);
  const int bx = wg & 15, by = wg >> 4; // NX=16
  const size_t m0 = (size_t)by * 128, n0 = (size_t)bx * 128;

  f32x4 acc[4][4] = {};

  const int srow = lane >> 3;
  const int sslot = ((lane & 7) ^ ((lane >> 3) & 7)) * 8;
  auto STAGE = [&](int buf, int k0) {
#pragma unroll
    for (int c = 0; c < 4; ++c) {
      const int seg = c * 4 + wave;
      const int r = seg * 8 + srow;
      llds16(As + buf * 8192 + seg * 512, A + (m0 + r) * (size_t)K + (k0 + sslot));
      llds16(Bs + buf * 8192 + seg * 512, Bw + (n0 + r) * (size_t)K + (k0 + sslot));
    }
  };

  bf16x4 rsdb[16];
  auto RSD = [&](int j) {
    const int flat = tid * 4 + j * 1024;
    const int row = flat >> 7, c = flat & 127;
    rsdb[j] = *(const bf16x4*)&h1[(m0 + row) * (size_t)N + n0 + c];
  };

  STAGE(0, 0);                                    // 8 in flight
  // stage P/Q (tile's 128 cols) and mu/sig (128 rows) into extra LDS.
  // NOTE: global source must be PER-LANE (+lane*16B); LDS dest is uniform
  // base + lane*16 (m104). One llds16 on waves 0/1 -> absorbed by vmcnt(10).
  if (wave == 0)
    llds16((u16*)extra,         (const u16*)(PQ + 2 * n0) + lane * 8);
  else if (wave == 1)
    llds16((u16*)(extra + 256), (const u16*)(ST + 2 * m0) + lane * 8);

#pragma unroll
  for (int t = 0; t < 8; ++t) {
    const int cur = t & 1;
    if (t < 7) {
      STAGE(cur ^ 1, (t + 1) * 64);               // +8
      RSD(2 * t); RSD(2 * t + 1);                 // +2
      asm volatile("s_waitcnt vmcnt(10)" ::: "memory");  // tile t (+extra at t=0) landed
    } else {
      RSD(14); RSD(15);
      asm volatile("s_waitcnt vmcnt(4)" ::: "memory");   // STAGE(7) landed
    }
    __builtin_amdgcn_s_barrier();
    asm volatile("" ::: "memory");

    const u16* Ab = As + cur * 8192;
    const u16* Bb = Bs + cur * 8192;
#pragma unroll
    for (int ks = 0; ks < 2; ++ks) {
      bf16x8 af[4], bfr[4];
#pragma unroll
      for (int m = 0; m < 4; ++m)
        af[m] = *(const bf16x8*)&Ab[(wr + m * 16 + lrow) * 64 +
                                    ((unsigned)((ks * 4 + lk) ^ (lane & 7))) * 8];
#pragma unroll
      for (int n = 0; n < 4; ++n)
        bfr[n] = *(const bf16x8*)&Bb[(wc + n * 16 + lrow) * 64 +
                                     ((unsigned)((ks * 4 + lk) ^ (lane & 7))) * 8];
      __builtin_amdgcn_s_setprio(1);
#pragma unroll
      for (int m = 0; m < 4; ++m)
#pragma unroll
        for (int n = 0; n < 4; ++n)
          acc[m][n] = __builtin_amdgcn_mfma_f32_16x16x32_bf16(af[m], bfr[n],
                                                              acc[m][n], 0, 0, 0);
      __builtin_amdgcn_s_setprio(0);
    }
    asm volatile("s_waitcnt lgkmcnt(0)" ::: "memory");
    __builtin_amdgcn_s_barrier();
    asm volatile("" ::: "memory");
  }

  // epilogue: bias into Cs (rotated), transpose-read, add reconstructed resid
#pragma unroll
  for (int n = 0; n < 4; ++n) {
    const int c = wc + n * 16 + lrow;
    const float bv = bias[n0 + c];
#pragma unroll
    for (int m = 0; m < 4; ++m) {
#pragma unroll
      for (int r = 0; r < 4; ++r) {
        const int row = wr + m * 16 + lk * 4 + r;
        Cs[row * 128 + ((c + ((row >> 2) << 3)) & 127)] = acc[m][n][r] + bv;
      }
    }
  }
  asm volatile("s_waitcnt lgkmcnt(0)" ::: "memory");
  __builtin_amdgcn_s_barrier();
  asm volatile("" ::: "memory");

  // per-thread cols are j-invariant: (tid*4 + j*1024) & 127 == (tid*4) & 127
  const int c0col = (tid * 4) & 127;
  const f32x4 pqa = *(const f32x4*)&extra[2 * c0col];      // P0 Q0 P1 Q1
  const f32x4 pqb = *(const f32x4*)&extra[2 * c0col + 4];  // P2 Q2 P3 Q3
  const float Pv[4] = {pqa[0], pqa[2], pqb[0], pqb[2]};
  const float Qv[4] = {pqa[1], pqa[3], pqb[1], pqb[3]};

#pragma unroll
  for (int j = 0; j < 16; ++j) {
    const int flat = tid * 4 + j * 1024;
    const int row = flat >> 7, c = flat & 127;
    const f32x4 cc = *(const f32x4*)&Cs[row * 128 + ((c + ((row >> 2) << 3)) & 127)];
    const float2 ms = *(const float2*)&extra[256 + 2 * row];  // mu, sigma (broadcast)
    f32x4 o;
#pragma unroll
    for (int e = 0; e < 4; ++e) {
      const float hv = bf2f(rsdb[j][e]);
      o[e] = cc[e] + ms.y * (Pv[e] * hv - Qv[e]) + ms.x;
    }
    *(f32x4*)&outp[(m0 + row) * (size_t)N + n0 + c] = o;
  }
}

extern "C" void kernel_launch(void* const* d_in, const int* in_sizes, int n_in,
                              void* d_out, int out_size, void* d_ws, size_t ws_size,
                              hipStream_t stream) {
  const float* x         = (const float*)d_in[0];
  const float* down_w    = (const float*)d_in[1];
  const float* down_b    = (const float*)d_in[2];
  const float* up_w      = (const float*)d_in[3];
  const float* up_b      = (const float*)d_in[4];
  const float* ln_g      = (const float*)d_in[5];
  const float* ln_b      = (const float*)d_in[6];
  const float* down_loga = (const float*)d_in[7];
  const float* up_loga   = (const float*)d_in[8];
  const int*   lang      = (const int*)d_in[9];

  const int D = 2048, BNK = 512;
  const int M = in_sizes[0] / D;  // 16384

  char* ws = (char*)d_ws;
  u16*   h1  = (u16*)ws;                                   // [M][D] bf16
  u16*   h2  = (u16*)(ws + (size_t)M * D * 2);             // [M][BNK] bf16
  u16*   dwb = (u16*)(ws + (size_t)M * D * 2 + (size_t)M * BNK * 2);  // [BNK][D]
  u16*   uwb = dwb + (size_t)BNK * D;                      // [D][BNK]
  float* PQ  = (float*)(uwb + (size_t)D * BNK);            // [D][2] {1/g, lnb/g}
  float* ST  = PQ + 2 * (size_t)D;                         // [M][2] {mu, sigma}

  prep_weights<<<(BNK * D) / 256, 256, 0, stream>>>(down_w, up_w, down_loga,
                                                    up_loga, lang, ln_g, ln_b,
                                                    dwb, uwb, PQ);
  ln_kernel<<<M, 256, 0, stream>>>(x, ln_g, ln_b, h1, ST);
  gemm1<<<(M / 128) * (BNK / 128), 256, 0, stream>>>(h1, dwb, M, D, BNK / 128,
                                                     down_b, h2);
  gemm2<<<(M / 128) * (D / 128), 256, 0, stream>>>(h2, uwb, M, up_b, h1, PQ, ST,
                                                   (float*)d_out);
}